// Round 1
// baseline (217.900 us; speedup 1.0000x reference)
//
#include <hip/hip_runtime.h>
#include <cstdint>
#include <cstddef>

#define EPS 1e-8f

// Fixed problem instance
#define Bsz 8
#define Nn  5
#define Kk  5
#define Ll  128
#define Ff  768
#define Tt  11                 // 2N+1
#define KL  640                // K*L
#define ROWS_PER_B 2560        // N*Q*L
#define NROWS 20480
#define F4  192                // Ff/4
#define BN  40                 // B*N

// ---- stage1 geometry ----
#define S1_ROWS 16
#define S1_CH   (KL / S1_ROWS)     // 40 chunks per bn
#define S1_NBLK (BN * S1_CH)       // 1600 blocks
#define PART_STRIDE (3 * Ff)       // 2304 floats per record [B|I|All]
#define PART_STRIDE4 (PART_STRIDE / 4)  // 576

typedef float v2f __attribute__((ext_vector_type(2)));

// ---------------- Stage 1: masked partial sums (unchanged) ----------------
// 1600 blocks x 192 threads = 18.75 waves/CU. Lane owns one float4 column;
// 16 rows per block. Records {B,I,All}; O recovered as All-B-I downstream.
__global__ __launch_bounds__(192) void stage1(
    const float* __restrict__ sup,      // [B][N][K][L][F]
    const int*   __restrict__ Bm,       // [B][N][K][L]
    const int*   __restrict__ Im,
    float* __restrict__ part,           // [S1_NBLK][3][Ff]
    float* __restrict__ pcnt)           // [S1_NBLK][2]
{
    int blk = blockIdx.x;
    int bn  = blk / S1_CH;
    int ch  = blk - bn * S1_CH;
    int tid = threadIdx.x;

    const float4* sp = (const float4*)(sup + ((size_t)bn * KL + ch * S1_ROWS) * Ff) + tid;
    const int*    bp = Bm + bn * KL + ch * S1_ROWS;   // block-uniform -> s_load
    const int*    ip = Im + bn * KL + ch * S1_ROWS;

    v2f tB0 = {0.f,0.f}, tB1 = tB0, tI0 = tB0, tI1 = tB0, tA0 = tB0, tA1 = tB0;
    int cB = 0, cI = 0;

    #pragma unroll
    for (int h = 0; h < 2; ++h) {
        float4 v[8];
        #pragma unroll
        for (int j = 0; j < 8; ++j) v[j] = sp[(h * 8 + j) * F4];
        #pragma unroll
        for (int j = 0; j < 8; ++j) {
            int p = h * 8 + j;
            v2f lo = {v[j].x, v[j].y};
            v2f hi = {v[j].z, v[j].w};
            tA0 += lo; tA1 += hi;
            if (bp[p]) { tB0 += lo; tB1 += hi; ++cB; }
            if (ip[p]) { tI0 += lo; tI1 += hi; ++cI; }
        }
    }

    float4* o = (float4*)(part + (size_t)blk * PART_STRIDE);
    float4 rB = {tB0.x, tB0.y, tB1.x, tB1.y};
    float4 rI = {tI0.x, tI0.y, tI1.x, tI1.y};
    float4 rA = {tA0.x, tA0.y, tA1.x, tA1.y};
    o[tid]          = rB;
    o[F4 + tid]     = rI;
    o[2 * F4 + tid] = rA;

    if (tid == 0) {
        pcnt[2 * (size_t)blk]     = (float)cB;
        pcnt[2 * (size_t)blk + 1] = (float)cI;
    }
}

// ---------------- Stage 2: reduce 40 chunks -> bnsum + mask counts ----------------
// 120 blocks x 768 threads (12 waves) = 5.6 waves/CU (was 1.4).
// Block = (bn,set). Thread (quarter q, f4) sums 10 chunks; LDS tree combines
// the 4 quarters. First wave of set<2 blocks also reduces pcnt -> cnt[bn][set].
// Deterministic (no global atomics).
__global__ __launch_bounds__(768) void stage2(
    const float* __restrict__ part,     // [S1_NBLK][3][Ff]
    const float* __restrict__ pcnt,     // [S1_NBLK][2]
    float* __restrict__ bnsum,          // [BN][3][Ff]
    float* __restrict__ cnt,            // [BN][2]
    float* __restrict__ loss_out)
{
    __shared__ float4 red[768];         // 12,288 B

    int blk = blockIdx.x;               // bn*3 + set
    int bn  = blk / 3;
    int set = blk - bn * 3;
    int tid = threadIdx.x;

    if (blk == 0 && tid == 0) loss_out[0] = 0.0f;

    int q  = tid / F4;                  // 0..3
    int f4 = tid - q * F4;              // 0..191

    const float4* src = (const float4*)part + ((size_t)bn * 3 * S1_CH + set) * F4 + f4;
    float4 s = {0, 0, 0, 0};
    float4 v[10];
    #pragma unroll
    for (int k = 0; k < 10; ++k) v[k] = src[(size_t)(q * 10 + k) * PART_STRIDE4];
    #pragma unroll
    for (int k = 0; k < 10; ++k) {
        s.x += v[k].x; s.y += v[k].y; s.z += v[k].z; s.w += v[k].w;
    }
    red[tid] = s;

    // pcnt reduction: first wave only, set<2 blocks
    if (set < 2 && tid < 64) {
        float cv = (tid < S1_CH) ? pcnt[2 * ((size_t)bn * S1_CH + tid) + set] : 0.0f;
        #pragma unroll
        for (int off = 32; off > 0; off >>= 1) cv += __shfl_xor(cv, off, 64);
        if (tid == 0) cnt[2 * bn + set] = cv;
    }

    __syncthreads();
    if (q == 0) {
        float4 a = red[f4];
        float4 b = red[F4 + f4];
        float4 c = red[2 * F4 + f4];
        float4 d = red[3 * F4 + f4];
        float4 t4 = {a.x + b.x + c.x + d.x, a.y + b.y + c.y + d.y,
                     a.z + b.z + c.z + d.z, a.w + b.w + c.w + d.w};
        ((float4*)bnsum)[((size_t)bn * 3 + set) * F4 + f4] = t4;
    }
}

// ---------------- Stage 2b: build scaled prototypes ONCE ----------------
// 88 blocks (b x t) x 192 threads. proto[b][t][f] = scaled prototype.
// t=0 -> O = sum_n(All-B-I) / (cO+eps); else (n,set) / (cnt+eps).
// Removes the redundant per-block scale/O recompute from stage3.
__global__ __launch_bounds__(192) void stage2b(
    const float* __restrict__ bnsum,    // [BN][3][Ff]
    const float* __restrict__ cnt,      // [BN][2]
    float* __restrict__ proto)          // [Bsz][Tt][Ff]
{
    int b  = blockIdx.x / Tt;
    int t  = blockIdx.x - b * Tt;
    int f4 = threadIdx.x;

    const float4* bs = (const float4*)bnsum + (size_t)b * Nn * 3 * F4;

    float scale;
    if (t == 0) {
        float cO = (float)(KL * Nn);
        #pragma unroll
        for (int k = 0; k < 2 * Nn; ++k) cO -= cnt[2 * Nn * b + k];
        scale = 1.0f / (cO + EPS);
    } else {
        scale = 1.0f / (cnt[2 * Nn * b + (t - 1)] + EPS);
    }

    float4 val;
    if (t == 0) {
        float sx = 0, sy = 0, sz = 0, sw = 0;
        #pragma unroll
        for (int n = 0; n < Nn; ++n) {
            float4 A  = bs[(n * 3 + 2) * F4 + f4];
            float4 Bv = bs[(n * 3 + 0) * F4 + f4];
            float4 Iv = bs[(n * 3 + 1) * F4 + f4];
            sx += A.x - Bv.x - Iv.x; sy += A.y - Bv.y - Iv.y;
            sz += A.z - Bv.z - Iv.z; sw += A.w - Bv.w - Iv.w;
        }
        val.x = sx; val.y = sy; val.z = sz; val.w = sw;
    } else {
        int n  = (t - 1) >> 1;
        int st = (t - 1) & 1;
        val = bs[(n * 3 + st) * F4 + f4];
    }
    val.x *= scale; val.y *= scale; val.z *= scale; val.w *= scale;
    ((float4*)proto)[((size_t)b * Tt + t) * F4 + f4] = val;
}

// ---------------- Stage 3: logits + argmax + NLL ----------------
// 640 blocks x 256 threads (4 waves) = 10 waves/CU (was 2.5). Block = 32 rows.
// Thread = 2 rows x 1/16-row with STRIDE-16 fragment interleave: at each j the
// 16 lanes of a fragment group read 256 B contiguous query (coalesced) and 16
// consecutive LDS float4s (2-way bank wrap = free). Prologue is a straight
// coalesced copy of precomputed proto (33.8 KB -> 4 blocks/CU LDS cap).
#define S3_ROWS 32
#define S3_NBLK (NROWS / S3_ROWS)          // 640
#define S3_BPB  (ROWS_PER_B / S3_ROWS)     // 80

#define DOT_STEP(JV, UU, WW)                                              \
    {                                                                     \
        _Pragma("unroll")                                                 \
        for (int t = 0; t < Tt; ++t) {                                    \
            float4 pv = pb[t * F4 + (JV) * 16];                           \
            float d0 = a0[t], d1 = a1[t];                                 \
            d0 = fmaf((UU).x, pv.x, d0); d0 = fmaf((UU).y, pv.y, d0);     \
            d0 = fmaf((UU).z, pv.z, d0); d0 = fmaf((UU).w, pv.w, d0);     \
            d1 = fmaf((WW).x, pv.x, d1); d1 = fmaf((WW).y, pv.y, d1);     \
            d1 = fmaf((WW).z, pv.z, d1); d1 = fmaf((WW).w, pv.w, d1);     \
            a0[t] = d0; a1[t] = d1;                                       \
        }                                                                 \
    }

__global__ __launch_bounds__(256, 3) void stage3(
    const float* __restrict__ query,    // [B][2560][Ff]
    const float* __restrict__ proto,    // [Bsz][Tt][Ff]
    const int*   __restrict__ label,    // [NROWS]
    float* __restrict__ out_logits,     // [NROWS][Tt]
    float* __restrict__ out_pred,       // [NROWS]
    float* __restrict__ loss_out)       // [1]
{
    __shared__ float4 ldsP[Tt * F4];    // 33,792 B

    int blk = blockIdx.x;
    int b   = blk / S3_BPB;
    int tid = threadIdx.x;

    // coalesced proto -> LDS copy (layout identical: [t][f4])
    const float4* pp = (const float4*)proto + (size_t)b * Tt * F4;
    for (int idx = tid; idx < Tt * F4; idx += 256) ldsP[idx] = pp[idx];
    __syncthreads();

    int p = tid >> 4;                   // row-pair 0..15
    int s = tid & 15;                   // fragment 0..15 (stride-16 interleave)

    size_t row0 = (size_t)blk * S3_ROWS + p * 2;
    const float4* q0 = (const float4*)query + row0 * F4 + s;
    const float4* q1 = q0 + F4;

    float a0[Tt], a1[Tt];
    #pragma unroll
    for (int t = 0; t < Tt; ++t) { a0[t] = 0.0f; a1[t] = 0.0f; }

    // double-buffered 6+6 query preload (24 float4 in flight)
    float4 u0[6], w0[6], u1[6], w1[6];
    #pragma unroll
    for (int j = 0; j < 6; ++j) { u0[j] = q0[j * 16]; w0[j] = q1[j * 16]; }
    #pragma unroll
    for (int j = 0; j < 6; ++j) { u1[j] = q0[(j + 6) * 16]; w1[j] = q1[(j + 6) * 16]; }

    const float4* pb = ldsP + s;
    #pragma unroll
    for (int j = 0; j < 6; ++j) DOT_STEP(j, u0[j], w0[j]);
    #pragma unroll
    for (int j = 0; j < 6; ++j) DOT_STEP(j + 6, u1[j], w1[j]);

    // reduce across the 16 fragment lanes
    #pragma unroll
    for (int t = 0; t < Tt; ++t) {
        a0[t] += __shfl_xor(a0[t], 1, 16); a0[t] += __shfl_xor(a0[t], 2, 16);
        a0[t] += __shfl_xor(a0[t], 4, 16); a0[t] += __shfl_xor(a0[t], 8, 16);
        a1[t] += __shfl_xor(a1[t], 1, 16); a1[t] += __shfl_xor(a1[t], 2, 16);
        a1[t] += __shfl_xor(a1[t], 4, 16); a1[t] += __shfl_xor(a1[t], 8, 16);
    }

    // epilogue: lane s==0 -> row0, lane s==1 -> row1 (both have full sums)
    float wloss = 0.0f;
    if (s < 2) {
        float rv[Tt];
        #pragma unroll
        for (int t = 0; t < Tt; ++t) rv[t] = s ? a1[t] : a0[t];
        size_t grow = row0 + s;

        float m = rv[0]; int bt = 0;
        #pragma unroll
        for (int t = 1; t < Tt; ++t) if (rv[t] > m) { m = rv[t]; bt = t; }  // first-max
        float sum = 0.0f;
        #pragma unroll
        for (int t = 0; t < Tt; ++t) sum += __expf(rv[t] - m);
        int lab = label[grow];
        float labv = rv[0];
        #pragma unroll
        for (int t = 1; t < Tt; ++t) labv = (lab == t) ? rv[t] : labv;
        #pragma unroll
        for (int t = 0; t < Tt; ++t) out_logits[grow * Tt + t] = rv[t];
        out_pred[grow] = (float)bt;
        wloss = (m + __logf(sum)) - labv;
    }
    #pragma unroll
    for (int off = 32; off > 0; off >>= 1) wloss += __shfl_xor(wloss, off, 64);
    if ((tid & 63) == 0) atomicAdd(loss_out, wloss * (1.0f / (float)NROWS));
}

// ---------------- Host launch ----------------
extern "C" void kernel_launch(void* const* d_in, const int* in_sizes, int n_in,
                              void* d_out, int out_size, void* d_ws, size_t ws_size,
                              hipStream_t stream) {
    const float* sup   = (const float*)d_in[0];
    const float* query = (const float*)d_in[1];
    const int*   Bm    = (const int*)d_in[2];
    const int*   Im    = (const int*)d_in[3];
    const int*   lab   = (const int*)d_in[4];

    // ws layout: part [1600][2304] | pcnt [1600][2] | bnsum [40][3][768]
    //            | cnt [40][2] | proto [8][11][768]
    float* w     = (float*)d_ws;
    float* part  = w;
    float* pcnt  = part + (size_t)S1_NBLK * PART_STRIDE;   // +3,686,400
    float* bnsum = pcnt + 2 * S1_NBLK;                     // +3,200
    float* cnt   = bnsum + (size_t)BN * 3 * Ff;            // +92,160
    float* proto = cnt + 2 * BN;                           // +80 (16B-aligned)

    float* loss_out   = (float*)d_out;
    float* out_logits = (float*)d_out + 1;
    float* out_pred   = (float*)d_out + 1 + (size_t)NROWS * Tt;

    stage1<<<S1_NBLK, 192, 0, stream>>>(sup, Bm, Im, part, pcnt);
    stage2<<<3 * BN, 768, 0, stream>>>(part, pcnt, bnsum, cnt, loss_out);
    stage2b<<<Bsz * Tt, 192, 0, stream>>>(bnsum, cnt, proto);
    stage3<<<S3_NBLK, 256, 0, stream>>>(query, proto, lab,
                                        out_logits, out_pred, loss_out);
}

// Round 2
// 195.476 us; speedup vs baseline: 1.1147x; 1.1147x over previous
//
#include <hip/hip_runtime.h>
#include <cstdint>
#include <cstddef>

#define EPS 1e-8f

// Fixed problem instance
#define Bsz 8
#define Nn  5
#define Kk  5
#define Ll  128
#define Ff  768
#define Tt  11                 // 2N+1
#define KL  640                // K*L
#define ROWS_PER_B 2560        // N*Q*L
#define NROWS 20480
#define F4  192                // Ff/4
#define BN  40                 // B*N

// ---- stage1 geometry ----
#define S1_ROWS 64
#define S1_CH   (KL / S1_ROWS)     // 10 chunks per bn
#define S1_NBLK (BN * S1_CH)       // 400 blocks
#define PART_STRIDE (3 * Ff)       // 2304 floats per record [B|I|All]
#define PART_STRIDE4 (PART_STRIDE / 4)  // 576

typedef float v2f __attribute__((ext_vector_type(2)));

// ---------------- Stage 1: masked partial sums ----------------
// 400 blocks x 192 threads. Lane owns one float4 column; 64 rows per block
// (4x fewer part-write bytes than 16-row version). Records {B,I,All};
// O recovered as All-B-I downstream. Masks block-uniform -> scalar loads.
__global__ __launch_bounds__(192) void stage1(
    const float* __restrict__ sup,      // [B][N][K][L][F]
    const int*   __restrict__ Bm,       // [B][N][K][L]
    const int*   __restrict__ Im,
    float* __restrict__ part,           // [S1_NBLK][3][Ff]
    float* __restrict__ pcnt)           // [S1_NBLK][2]
{
    int blk = blockIdx.x;
    int bn  = blk / S1_CH;
    int ch  = blk - bn * S1_CH;
    int tid = threadIdx.x;

    const float4* sp = (const float4*)(sup + ((size_t)bn * KL + ch * S1_ROWS) * Ff) + tid;
    const int*    bp = Bm + bn * KL + ch * S1_ROWS;   // block-uniform
    const int*    ip = Im + bn * KL + ch * S1_ROWS;

    v2f tB0 = {0.f,0.f}, tB1 = tB0, tI0 = tB0, tI1 = tB0, tA0 = tB0, tA1 = tB0;
    int cB = 0, cI = 0;

    for (int h = 0; h < S1_ROWS / 8; ++h) {
        float4 v[8];
        #pragma unroll
        for (int j = 0; j < 8; ++j) v[j] = sp[(size_t)(h * 8 + j) * F4];
        #pragma unroll
        for (int j = 0; j < 8; ++j) {
            int p = h * 8 + j;
            v2f lo = {v[j].x, v[j].y};
            v2f hi = {v[j].z, v[j].w};
            tA0 += lo; tA1 += hi;
            if (bp[p]) { tB0 += lo; tB1 += hi; ++cB; }
            if (ip[p]) { tI0 += lo; tI1 += hi; ++cI; }
        }
    }

    float4* o = (float4*)(part + (size_t)blk * PART_STRIDE);
    float4 rB = {tB0.x, tB0.y, tB1.x, tB1.y};
    float4 rI = {tI0.x, tI0.y, tI1.x, tI1.y};
    float4 rA = {tA0.x, tA0.y, tA1.x, tA1.y};
    o[tid]          = rB;
    o[F4 + tid]     = rI;
    o[2 * F4 + tid] = rA;

    if (tid == 0) {
        pcnt[2 * (size_t)blk]     = (float)cB;
        pcnt[2 * (size_t)blk + 1] = (float)cI;
    }
}

// ---------------- Stage 2: reduce 10 chunks -> bnsum + mask counts ----------------
// 90 blocks x 256 = 23,040 threads = one per (bn, set, f4). 10-deep batched
// loads. First 80 gids also reduce pcnt -> cnt[bn][set]. Deterministic.
__global__ __launch_bounds__(256) void stage2(
    const float* __restrict__ part,     // [S1_NBLK][3][Ff]
    const float* __restrict__ pcnt,     // [S1_NBLK][2]
    float* __restrict__ bnsum,          // [BN][3][Ff]
    float* __restrict__ cnt,            // [BN][2]
    float* __restrict__ loss_out)
{
    int gid = blockIdx.x * 256 + threadIdx.x;
    if (gid == 0) loss_out[0] = 0.0f;

    int bn  = gid / (3 * F4);
    int r   = gid - bn * (3 * F4);
    int set = r / F4;
    int f4  = r - set * F4;

    const float4* src = (const float4*)part + ((size_t)bn * S1_CH * 3 + set) * F4 + f4;
    float4 s = {0, 0, 0, 0};
    float4 v[S1_CH];
    #pragma unroll
    for (int c = 0; c < S1_CH; ++c) v[c] = src[(size_t)c * PART_STRIDE4];
    #pragma unroll
    for (int c = 0; c < S1_CH; ++c) {
        s.x += v[c].x; s.y += v[c].y; s.z += v[c].z; s.w += v[c].w;
    }
    ((float4*)bnsum)[((size_t)bn * 3 + set) * F4 + f4] = s;

    // pcnt reduction: gid < 80 -> (b*n, set)
    if (gid < 2 * BN) {
        int bn2  = gid >> 1;
        int set2 = gid & 1;
        float cv = 0.0f;
        #pragma unroll
        for (int c = 0; c < S1_CH; ++c) cv += pcnt[2 * ((size_t)bn2 * S1_CH + c) + set2];
        cnt[gid] = cv;
    }
}

// ---------------- Stage 2b: build scaled prototypes ONCE ----------------
// 88 blocks (b x t) x 192 threads. proto[b][t][f] = scaled prototype.
__global__ __launch_bounds__(192) void stage2b(
    const float* __restrict__ bnsum,    // [BN][3][Ff]
    const float* __restrict__ cnt,      // [BN][2]
    float* __restrict__ proto)          // [Bsz][Tt][Ff]
{
    int b  = blockIdx.x / Tt;
    int t  = blockIdx.x - b * Tt;
    int f4 = threadIdx.x;

    const float4* bs = (const float4*)bnsum + (size_t)b * Nn * 3 * F4;

    float scale;
    if (t == 0) {
        float cO = (float)(KL * Nn);
        #pragma unroll
        for (int k = 0; k < 2 * Nn; ++k) cO -= cnt[2 * Nn * b + k];
        scale = 1.0f / (cO + EPS);
    } else {
        scale = 1.0f / (cnt[2 * Nn * b + (t - 1)] + EPS);
    }

    float4 val;
    if (t == 0) {
        float sx = 0, sy = 0, sz = 0, sw = 0;
        #pragma unroll
        for (int n = 0; n < Nn; ++n) {
            float4 A  = bs[(n * 3 + 2) * F4 + f4];
            float4 Bv = bs[(n * 3 + 0) * F4 + f4];
            float4 Iv = bs[(n * 3 + 1) * F4 + f4];
            sx += A.x - Bv.x - Iv.x; sy += A.y - Bv.y - Iv.y;
            sz += A.z - Bv.z - Iv.z; sw += A.w - Bv.w - Iv.w;
        }
        val.x = sx; val.y = sy; val.z = sz; val.w = sw;
    } else {
        int n  = (t - 1) >> 1;
        int st = (t - 1) & 1;
        val = bs[(n * 3 + st) * F4 + f4];
    }
    val.x *= scale; val.y *= scale; val.z *= scale; val.w *= scale;
    ((float4*)proto)[((size_t)b * Tt + t) * F4 + f4] = val;
}

// ---------------- Stage 3: logits + argmax + NLL ----------------
// 320 blocks x 256 threads. Thread = 4 consecutive rows x 1/16-fragment:
// each LDS pv read now feeds 16 FMA (was 8) -> LDS read traffic halved
// (693 -> 347 MB). Query loads double-buffered per j-step (sustained MLP,
// no one-shot burst). Loss: block-LDS reduce -> ONE atomic per block.
#define S3_ROWS 64
#define S3_NBLK (NROWS / S3_ROWS)          // 320

__global__ __launch_bounds__(256) void stage3(
    const float* __restrict__ query,    // [B][2560][Ff]
    const float* __restrict__ proto,    // [Bsz][Tt][Ff]
    const int*   __restrict__ label,    // [NROWS]
    float* __restrict__ out_logits,     // [NROWS][Tt]
    float* __restrict__ out_pred,       // [NROWS]
    float* __restrict__ loss_out)       // [1]
{
    __shared__ float4 ldsP[Tt * F4];    // 33,792 B
    __shared__ float  lred[4];

    int blk = blockIdx.x;
    int tid = threadIdx.x;
    int b   = blk / (ROWS_PER_B / S3_ROWS);

    // coalesced proto -> LDS copy (layout identical: [t][f4])
    const float4* pp = (const float4*)proto + (size_t)b * Tt * F4;
    for (int idx = tid; idx < Tt * F4; idx += 256) ldsP[idx] = pp[idx];
    __syncthreads();

    int p = tid >> 4;                   // row-quad 0..15
    int s = tid & 15;                   // fragment 0..15

    size_t row0 = (size_t)blk * S3_ROWS + p * 4;
    const float4* qb = (const float4*)query + row0 * F4 + s;

    float a0[Tt], a1[Tt], a2[Tt], a3[Tt];
    #pragma unroll
    for (int t = 0; t < Tt; ++t) { a0[t] = 0.f; a1[t] = 0.f; a2[t] = 0.f; a3[t] = 0.f; }

    // double-buffered 4-row loads
    float4 u0 = qb[0 * F4], u1 = qb[1 * F4], u2 = qb[2 * F4], u3 = qb[3 * F4];

    const float4* pb = ldsP + s;
    #pragma unroll
    for (int j = 0; j < 12; ++j) {
        float4 w0, w1, w2, w3;
        if (j < 11) {
            int o = (j + 1) * 16;
            w0 = qb[0 * F4 + o]; w1 = qb[1 * F4 + o];
            w2 = qb[2 * F4 + o]; w3 = qb[3 * F4 + o];
        }
        #pragma unroll
        for (int t = 0; t < Tt; ++t) {
            float4 pv = pb[t * F4 + j * 16];
            float d0 = a0[t], d1 = a1[t], d2 = a2[t], d3 = a3[t];
            d0 = fmaf(u0.x, pv.x, d0); d0 = fmaf(u0.y, pv.y, d0);
            d0 = fmaf(u0.z, pv.z, d0); d0 = fmaf(u0.w, pv.w, d0);
            d1 = fmaf(u1.x, pv.x, d1); d1 = fmaf(u1.y, pv.y, d1);
            d1 = fmaf(u1.z, pv.z, d1); d1 = fmaf(u1.w, pv.w, d1);
            d2 = fmaf(u2.x, pv.x, d2); d2 = fmaf(u2.y, pv.y, d2);
            d2 = fmaf(u2.z, pv.z, d2); d2 = fmaf(u2.w, pv.w, d2);
            d3 = fmaf(u3.x, pv.x, d3); d3 = fmaf(u3.y, pv.y, d3);
            d3 = fmaf(u3.z, pv.z, d3); d3 = fmaf(u3.w, pv.w, d3);
            a0[t] = d0; a1[t] = d1; a2[t] = d2; a3[t] = d3;
        }
        if (j < 11) { u0 = w0; u1 = w1; u2 = w2; u3 = w3; }
    }

    // reduce across the 16 fragment lanes
    #pragma unroll
    for (int t = 0; t < Tt; ++t) {
        a0[t] += __shfl_xor(a0[t], 1, 16); a0[t] += __shfl_xor(a0[t], 2, 16);
        a0[t] += __shfl_xor(a0[t], 4, 16); a0[t] += __shfl_xor(a0[t], 8, 16);
        a1[t] += __shfl_xor(a1[t], 1, 16); a1[t] += __shfl_xor(a1[t], 2, 16);
        a1[t] += __shfl_xor(a1[t], 4, 16); a1[t] += __shfl_xor(a1[t], 8, 16);
        a2[t] += __shfl_xor(a2[t], 1, 16); a2[t] += __shfl_xor(a2[t], 2, 16);
        a2[t] += __shfl_xor(a2[t], 4, 16); a2[t] += __shfl_xor(a2[t], 8, 16);
        a3[t] += __shfl_xor(a3[t], 1, 16); a3[t] += __shfl_xor(a3[t], 2, 16);
        a3[t] += __shfl_xor(a3[t], 4, 16); a3[t] += __shfl_xor(a3[t], 8, 16);
    }

    // epilogue: lane s (<4) handles row row0+s (compile-time select chain)
    float wloss = 0.0f;
    if (s < 4) {
        float rv[Tt];
        #pragma unroll
        for (int t = 0; t < Tt; ++t)
            rv[t] = (s == 0) ? a0[t] : (s == 1) ? a1[t] : (s == 2) ? a2[t] : a3[t];
        size_t grow = row0 + s;

        float m = rv[0]; int bt = 0;
        #pragma unroll
        for (int t = 1; t < Tt; ++t) if (rv[t] > m) { m = rv[t]; bt = t; }  // first-max
        float sum = 0.0f;
        #pragma unroll
        for (int t = 0; t < Tt; ++t) sum += __expf(rv[t] - m);
        int lab = label[grow];
        float labv = rv[0];
        #pragma unroll
        for (int t = 1; t < Tt; ++t) labv = (lab == t) ? rv[t] : labv;
        #pragma unroll
        for (int t = 0; t < Tt; ++t) out_logits[grow * Tt + t] = rv[t];
        out_pred[grow] = (float)bt;
        wloss = (m + __logf(sum)) - labv;
    }
    // block loss reduce -> one atomic per block
    #pragma unroll
    for (int off = 32; off > 0; off >>= 1) wloss += __shfl_xor(wloss, off, 64);
    if ((tid & 63) == 0) lred[tid >> 6] = wloss;
    __syncthreads();
    if (tid == 0)
        atomicAdd(loss_out, (lred[0] + lred[1] + lred[2] + lred[3]) * (1.0f / (float)NROWS));
}

// ---------------- Host launch ----------------
extern "C" void kernel_launch(void* const* d_in, const int* in_sizes, int n_in,
                              void* d_out, int out_size, void* d_ws, size_t ws_size,
                              hipStream_t stream) {
    const float* sup   = (const float*)d_in[0];
    const float* query = (const float*)d_in[1];
    const int*   Bm    = (const int*)d_in[2];
    const int*   Im    = (const int*)d_in[3];
    const int*   lab   = (const int*)d_in[4];

    // ws layout: part [400][2304] | pcnt [400][2] | bnsum [40][3][768]
    //            | cnt [40][2] | proto [8][11][768]
    float* w     = (float*)d_ws;
    float* part  = w;
    float* pcnt  = part + (size_t)S1_NBLK * PART_STRIDE;   // +921,600
    float* bnsum = pcnt + 2 * S1_NBLK;                     // +800
    float* cnt   = bnsum + (size_t)BN * 3 * Ff;            // +92,160
    float* proto = cnt + 2 * BN;                           // +80 (16B-aligned)

    float* loss_out   = (float*)d_out;
    float* out_logits = (float*)d_out + 1;
    float* out_pred   = (float*)d_out + 1 + (size_t)NROWS * Tt;

    stage1<<<S1_NBLK, 192, 0, stream>>>(sup, Bm, Im, part, pcnt);
    stage2<<<90, 256, 0, stream>>>(part, pcnt, bnsum, cnt, loss_out);
    stage2b<<<Bsz * Tt, 192, 0, stream>>>(bnsum, cnt, proto);
    stage3<<<S3_NBLK, 256, 0, stream>>>(query, proto, lab,
                                        out_logits, out_pred, loss_out);
}

// Round 3
// 195.222 us; speedup vs baseline: 1.1162x; 1.0013x over previous
//
#include <hip/hip_runtime.h>
#include <cstdint>
#include <cstddef>

#define EPS 1e-8f

// Fixed problem instance
#define Bsz 8
#define Nn  5
#define Kk  5
#define Ll  128
#define Ff  768
#define Tt  11                 // 2N+1
#define KL  640                // K*L
#define ROWS_PER_B 2560        // N*Q*L
#define NROWS 20480
#define F4  192                // Ff/4
#define BN  40                 // B*N

// ---- stage1 geometry ----
#define S1_ROWS 64
#define S1_G    4                  // row-groups per block
#define S1_GR   16                 // rows per group
#define S1_CH   (KL / S1_ROWS)     // 10 chunks per bn
#define S1_NBLK (BN * S1_CH)       // 400 blocks
#define PART_STRIDE (3 * Ff)       // 2304 floats per record [B|I|All]
#define PART_STRIDE4 (PART_STRIDE / 4)  // 576

typedef float v2f __attribute__((ext_vector_type(2)));

// ---------------- Stage 1: masked partial sums ----------------
// 400 blocks x 768 threads (12 waves -> 4.7 waves/SIMD, was 1.17). Block =
// 64 rows as 4 groups x 16 rows; 192 lanes own one float4 column each.
// Groups combine via LDS tree -> one part record per block (small part kept).
__global__ __launch_bounds__(768) void stage1(
    const float* __restrict__ sup,      // [B][N][K][L][F]
    const int*   __restrict__ Bm,       // [B][N][K][L]
    const int*   __restrict__ Im,
    float* __restrict__ part,           // [S1_NBLK][3][Ff]
    float* __restrict__ pcnt)           // [S1_NBLK][2]
{
    __shared__ float4 red[S1_G * 3 * F4];   // 36,864 B
    __shared__ float  redc[S1_G * 2];

    int blk = blockIdx.x;
    int bn  = blk / S1_CH;
    int ch  = blk - bn * S1_CH;
    int tid = threadIdx.x;
    int g   = tid / 192;
    int col = tid - g * 192;
    int rbase = ch * S1_ROWS + g * S1_GR;

    const float4* sp = (const float4*)(sup + ((size_t)bn * KL + rbase) * Ff) + col;
    const int*    bp = Bm + bn * KL + rbase;   // group-uniform
    const int*    ip = Im + bn * KL + rbase;

    v2f tB0 = {0.f,0.f}, tB1 = tB0, tI0 = tB0, tI1 = tB0, tA0 = tB0, tA1 = tB0;
    int cB = 0, cI = 0;

    #pragma unroll
    for (int h = 0; h < S1_GR / 8; ++h) {
        float4 v[8];
        #pragma unroll
        for (int j = 0; j < 8; ++j) v[j] = sp[(size_t)(h * 8 + j) * F4];
        #pragma unroll
        for (int j = 0; j < 8; ++j) {
            int p = h * 8 + j;
            v2f lo = {v[j].x, v[j].y};
            v2f hi = {v[j].z, v[j].w};
            tA0 += lo; tA1 += hi;
            if (bp[p]) { tB0 += lo; tB1 += hi; ++cB; }
            if (ip[p]) { tI0 += lo; tI1 += hi; ++cI; }
        }
    }

    red[(g * 3 + 0) * F4 + col] = (float4){tB0.x, tB0.y, tB1.x, tB1.y};
    red[(g * 3 + 1) * F4 + col] = (float4){tI0.x, tI0.y, tI1.x, tI1.y};
    red[(g * 3 + 2) * F4 + col] = (float4){tA0.x, tA0.y, tA1.x, tA1.y};
    if (col == 0) { redc[g * 2] = (float)cB; redc[g * 2 + 1] = (float)cI; }
    __syncthreads();

    if (tid < 3 * F4) {
        int set = tid / F4;
        int c   = tid - set * F4;
        float4 a = red[(0 * 3 + set) * F4 + c];
        float4 b = red[(1 * 3 + set) * F4 + c];
        float4 d = red[(2 * 3 + set) * F4 + c];
        float4 e = red[(3 * 3 + set) * F4 + c];
        float4 s = {a.x + b.x + d.x + e.x, a.y + b.y + d.y + e.y,
                    a.z + b.z + d.z + e.z, a.w + b.w + d.w + e.w};
        ((float4*)(part + (size_t)blk * PART_STRIDE))[tid] = s;
    }
    if (tid == 0) {
        pcnt[2 * (size_t)blk]     = redc[0] + redc[2] + redc[4] + redc[6];
        pcnt[2 * (size_t)blk + 1] = redc[1] + redc[3] + redc[5] + redc[7];
    }
}

// ---------------- Stage 2 (fused): chunks -> scaled prototypes ----------------
// 32 blocks (b x F-quarter) x 512 threads. Reduces part slice + pcnt into LDS,
// then builds proto[b][t][slice] directly. Eliminates stage2b dispatch and the
// bnsum global round-trip.
#define S2_Q  4
#define S2_QF (F4 / S2_Q)   // 48 float4 per quarter

__global__ __launch_bounds__(512) void stage2f(
    const float* __restrict__ part,     // [S1_NBLK][3][Ff]
    const float* __restrict__ pcnt,     // [S1_NBLK][2]
    float* __restrict__ proto,          // [Bsz][Tt][Ff]
    float* __restrict__ loss_out)
{
    __shared__ float4 bns[Nn * 3 * S2_QF];   // 11,520 B
    __shared__ float  scnt[2 * Nn];

    int blk = blockIdx.x;
    int b   = blk / S2_Q;
    int q   = blk - b * S2_Q;
    int tid = threadIdx.x;

    if (blk == 0 && tid == 0) loss_out[0] = 0.0f;

    for (int it = tid; it < Nn * 3 * S2_QF; it += 512) {   // 720 items
        int n   = it / (3 * S2_QF);
        int r   = it - n * (3 * S2_QF);
        int set = r / S2_QF;
        int f   = r - set * S2_QF;
        const float4* src = (const float4*)part
            + ((size_t)((b * Nn + n) * S1_CH) * 3 + set) * F4 + (q * S2_QF + f);
        float4 s = {0, 0, 0, 0};
        float4 v[S1_CH];
        #pragma unroll
        for (int c = 0; c < S1_CH; ++c) v[c] = src[(size_t)c * PART_STRIDE4];
        #pragma unroll
        for (int c = 0; c < S1_CH; ++c) {
            s.x += v[c].x; s.y += v[c].y; s.z += v[c].z; s.w += v[c].w;
        }
        bns[it] = s;
    }
    if (tid < 2 * Nn) {
        int n = tid >> 1, set = tid & 1;
        float cv = 0.0f;
        #pragma unroll
        for (int c = 0; c < S1_CH; ++c)
            cv += pcnt[2 * ((size_t)(b * Nn + n) * S1_CH + c) + set];
        scnt[tid] = cv;                 // index 2n+set == t-1
    }
    __syncthreads();

    for (int it = tid; it < Tt * S2_QF; it += 512) {       // 528 items
        int t = it / S2_QF;
        int f = it - t * S2_QF;
        float scale;
        float4 val;
        if (t == 0) {
            float cO = (float)(KL * Nn);
            #pragma unroll
            for (int k = 0; k < 2 * Nn; ++k) cO -= scnt[k];
            scale = 1.0f / (cO + EPS);
            float sx = 0, sy = 0, sz = 0, sw = 0;
            #pragma unroll
            for (int n = 0; n < Nn; ++n) {
                float4 A  = bns[(n * 3 + 2) * S2_QF + f];
                float4 Bv = bns[(n * 3 + 0) * S2_QF + f];
                float4 Iv = bns[(n * 3 + 1) * S2_QF + f];
                sx += A.x - Bv.x - Iv.x; sy += A.y - Bv.y - Iv.y;
                sz += A.z - Bv.z - Iv.z; sw += A.w - Bv.w - Iv.w;
            }
            val = (float4){sx, sy, sz, sw};
        } else {
            int n  = (t - 1) >> 1;
            int st = (t - 1) & 1;
            scale = 1.0f / (scnt[t - 1] + EPS);
            val = bns[(n * 3 + st) * S2_QF + f];
        }
        val.x *= scale; val.y *= scale; val.z *= scale; val.w *= scale;
        ((float4*)proto)[((size_t)b * Tt + t) * F4 + q * S2_QF + f] = val;
    }
}

// ---------------- Stage 3: logits + argmax + NLL ----------------
// 320 blocks x 128 threads. Thread = 8 rows x 1/16-fragment: each LDS pv read
// feeds 32 FMA (was 16) -> LDS traffic 173 -> 87 MB. j-loop ROLLED (6 iters,
// 2 j-steps each, ~6 KB body) to stay inside the 32 KB I-cache; query loads
// double-buffered u/w. All acc indices compile-time (no scratch).
#define S3_ROWS 64
#define S3_NBLK (NROWS / S3_ROWS)          // 320

__global__ __launch_bounds__(128) void stage3(
    const float* __restrict__ query,    // [B][2560][Ff]
    const float* __restrict__ proto,    // [Bsz][Tt][Ff]
    const int*   __restrict__ label,    // [NROWS]
    float* __restrict__ out_logits,     // [NROWS][Tt]
    float* __restrict__ out_pred,       // [NROWS]
    float* __restrict__ loss_out)       // [1]
{
    __shared__ float4 ldsP[Tt * F4];    // 33,792 B
    __shared__ float  lred[2];

    int blk = blockIdx.x;
    int tid = threadIdx.x;
    int b   = blk / (ROWS_PER_B / S3_ROWS);

    const float4* pp = (const float4*)proto + (size_t)b * Tt * F4;
    for (int idx = tid; idx < Tt * F4; idx += 128) ldsP[idx] = pp[idx];
    __syncthreads();

    int p = tid >> 4;                   // row-oct 0..7
    int s = tid & 15;                   // fragment 0..15

    size_t row0 = (size_t)blk * S3_ROWS + p * 8;
    const float4* qb = (const float4*)query + row0 * F4 + s;

    float a[8][Tt];
    #pragma unroll
    for (int r = 0; r < 8; ++r)
        #pragma unroll
        for (int t = 0; t < Tt; ++t) a[r][t] = 0.0f;

    float4 u[8], w[8];
    #pragma unroll
    for (int r = 0; r < 8; ++r) u[r] = qb[r * F4];      // j=0

    const float4* pb = ldsP + s;
    for (int jj = 0; jj < 6; ++jj) {
        int j0 = 2 * jj, j1 = 2 * jj + 1;
        // prefetch j1 while computing j0
        #pragma unroll
        for (int r = 0; r < 8; ++r) w[r] = qb[r * F4 + j1 * 16];
        #pragma unroll
        for (int t = 0; t < Tt; ++t) {
            float4 pv = pb[t * F4 + j0 * 16];
            #pragma unroll
            for (int r = 0; r < 8; ++r) {
                float d = a[r][t];
                d = fmaf(u[r].x, pv.x, d); d = fmaf(u[r].y, pv.y, d);
                d = fmaf(u[r].z, pv.z, d); d = fmaf(u[r].w, pv.w, d);
                a[r][t] = d;
            }
        }
        // prefetch j0 of next iter while computing j1 (clamped on last iter)
        int o2 = (jj < 5) ? (2 * jj + 2) * 16 : 0;
        #pragma unroll
        for (int r = 0; r < 8; ++r) u[r] = qb[r * F4 + o2];
        #pragma unroll
        for (int t = 0; t < Tt; ++t) {
            float4 pv = pb[t * F4 + j1 * 16];
            #pragma unroll
            for (int r = 0; r < 8; ++r) {
                float d = a[r][t];
                d = fmaf(w[r].x, pv.x, d); d = fmaf(w[r].y, pv.y, d);
                d = fmaf(w[r].z, pv.z, d); d = fmaf(w[r].w, pv.w, d);
                a[r][t] = d;
            }
        }
    }

    // reduce across the 16 fragment lanes
    #pragma unroll
    for (int r = 0; r < 8; ++r)
        #pragma unroll
        for (int t = 0; t < Tt; ++t) {
            float v = a[r][t];
            v += __shfl_xor(v, 1, 16); v += __shfl_xor(v, 2, 16);
            v += __shfl_xor(v, 4, 16); v += __shfl_xor(v, 8, 16);
            a[r][t] = v;
        }

    // epilogue: lane s (<8) handles row row0+s (compile-time select chain)
    float wloss = 0.0f;
    if (s < 8) {
        float rv[Tt];
        #pragma unroll
        for (int t = 0; t < Tt; ++t)
            rv[t] = (s == 0) ? a[0][t] : (s == 1) ? a[1][t] : (s == 2) ? a[2][t]
                  : (s == 3) ? a[3][t] : (s == 4) ? a[4][t] : (s == 5) ? a[5][t]
                  : (s == 6) ? a[6][t] : a[7][t];
        size_t grow = row0 + s;

        float m = rv[0]; int bt = 0;
        #pragma unroll
        for (int t = 1; t < Tt; ++t) if (rv[t] > m) { m = rv[t]; bt = t; }  // first-max
        float sum = 0.0f;
        #pragma unroll
        for (int t = 0; t < Tt; ++t) sum += __expf(rv[t] - m);
        int lab = label[grow];
        float labv = rv[0];
        #pragma unroll
        for (int t = 1; t < Tt; ++t) labv = (lab == t) ? rv[t] : labv;
        #pragma unroll
        for (int t = 0; t < Tt; ++t) out_logits[grow * Tt + t] = rv[t];
        out_pred[grow] = (float)bt;
        wloss = (m + __logf(sum)) - labv;
    }
    // block loss reduce -> one atomic per block
    #pragma unroll
    for (int off = 32; off > 0; off >>= 1) wloss += __shfl_xor(wloss, off, 64);
    if ((tid & 63) == 0) lred[tid >> 6] = wloss;
    __syncthreads();
    if (tid == 0)
        atomicAdd(loss_out, (lred[0] + lred[1]) * (1.0f / (float)NROWS));
}

// ---------------- Host launch ----------------
extern "C" void kernel_launch(void* const* d_in, const int* in_sizes, int n_in,
                              void* d_out, int out_size, void* d_ws, size_t ws_size,
                              hipStream_t stream) {
    const float* sup   = (const float*)d_in[0];
    const float* query = (const float*)d_in[1];
    const int*   Bm    = (const int*)d_in[2];
    const int*   Im    = (const int*)d_in[3];
    const int*   lab   = (const int*)d_in[4];

    // ws layout: part [400][2304] | pcnt [400][2] | proto [8][11][768]
    float* w     = (float*)d_ws;
    float* part  = w;
    float* pcnt  = part + (size_t)S1_NBLK * PART_STRIDE;   // +921,600
    float* proto = pcnt + 2 * S1_NBLK;                     // +800 (16B-aligned)

    float* loss_out   = (float*)d_out;
    float* out_logits = (float*)d_out + 1;
    float* out_pred   = (float*)d_out + 1 + (size_t)NROWS * Tt;

    stage1<<<S1_NBLK, 768, 0, stream>>>(sup, Bm, Im, part, pcnt);
    stage2f<<<Bsz * S2_Q, 512, 0, stream>>>(part, pcnt, proto, loss_out);
    stage3<<<S3_NBLK, 128, 0, stream>>>(query, proto, lab,
                                        out_logits, out_pred, loss_out);
}